// Round 9
// baseline (468.058 us; speedup 1.0000x reference)
//
#include <hip/hip_runtime.h>
#include <stdint.h>

// MultiHeadedAttention: B=2,S=2048,D=1024,H=16,DK=64
// Pipeline: fused f32->f16 cvt; fused QKV proj GEMM (MFMA f16, Q pre-scaled
// by 0.125*log2e); batch-merged ZERO-BARRIER flash attention (K/V read
// directly global->registers, L2-resident; no LDS staging, no syncthreads;
// bias/mask prefetched one tile ahead in static double-buffered regs);
// out proj GEMM -> f32.

typedef _Float16 f16;
typedef _Float16 f16x8 __attribute__((ext_vector_type(8)));
typedef _Float16 f16x4 __attribute__((ext_vector_type(4)));
typedef __fp16 h2 __attribute__((ext_vector_type(2)));
typedef float f32x4 __attribute__((ext_vector_type(4)));

#define LOG2E 1.44269504088896340736f

__device__ __forceinline__ void gload16(const void* g, void* l) {
  __builtin_amdgcn_global_load_lds(
      (const __attribute__((address_space(1))) unsigned int*)g,
      (__attribute__((address_space(3))) unsigned int*)l, 16, 0, 0);
}

// ---------------- fused f32 -> f16 conversion ------------------------------
struct CvtSrcs { const float* s[7]; };

__global__ __launch_bounds__(256) void cvt_all(CvtSrcs a, f16* __restrict__ out) {
  const int i = blockIdx.x * 256 + threadIdx.x;  // 0 .. 4194303
  int r, base;
  if (i < 3145728) { r = i >> 20; base = r << 20; }
  else { r = 3 + ((i - 3145728) >> 18); base = 3145728 + ((r - 3) << 18); }
  const float4 v = ((const float4*)a.s[r])[i - base];
  f16x4 o = {(f16)v.x, (f16)v.y, (f16)v.z, (f16)v.w};
  ((f16x4*)out)[i] = o;
}

// ---------------- mask dtype classify + canonicalize to u8 ----------------
__global__ void mask_detect(const uint8_t* __restrict__ m, int* __restrict__ flag) {
  __shared__ int s_off, s_weird;
  const int t = threadIdx.x;
  if (t == 0) { s_off = 0; s_weird = 0; }
  __syncthreads();
  int f_off = 0, f_weird = 0;
  for (int i = t; i < 8192; i += 256) {
    const uint8_t v = m[i];
    if ((i & 3) && v) f_off = 1;
    if (v > 1) f_weird = 1;
  }
  if (f_off) atomicOr(&s_off, 1);
  if (f_weird) atomicOr(&s_weird, 1);
  __syncthreads();
  if (t == 0) *flag = (s_off && !s_weird) ? 1 : 0;  // 1 => byte-sized bool
}

__global__ __launch_bounds__(256) void mask_canon(const uint8_t* __restrict__ m,
                                                  uint8_t* __restrict__ out,
                                                  const int* __restrict__ flag) {
  const int i = (blockIdx.x * 256 + threadIdx.x) * 4;  // grid covers 8388608
  uchar4 o;
  if (*flag) {
    const uchar4 v = *(const uchar4*)(m + i);
    o = make_uchar4(v.x != 0, v.y != 0, v.z != 0, v.w != 0);
  } else {
    const int4 v = *(const int4*)((const int*)m + i);
    o = make_uchar4(v.x != 0, v.y != 0, v.z != 0, v.w != 0);
  }
  *(uchar4*)(out + i) = o;
}

// ---------------- fused QKV projection GEMM --------------------------------
__global__ __launch_bounds__(256, 2) void gemm_qkv(
    const f16* __restrict__ qh, const f16* __restrict__ kh, const f16* __restrict__ vh,
    const f16* __restrict__ wq, const f16* __restrict__ wk, const f16* __restrict__ wv,
    const float* __restrict__ bq, const float* __restrict__ bk, const float* __restrict__ bv,
    f16* __restrict__ Qp, f16* __restrict__ Kp, f16* __restrict__ Vt) {
  constexpr int K = 1024;
  const int t = threadIdx.x;
  const int w = t >> 6, lane = t & 63, l15 = lane & 15, l4 = lane >> 4;
  const int nt = (int)blockIdx.x % 48;
  const int bm = ((int)blockIdx.x / 48) * 128;
  const int which = nt >> 4;
  const int bn = (nt & 15) * 64;
  const f16* A = which == 0 ? qh : which == 1 ? kh : vh;
  const f16* Bw = which == 0 ? wq : which == 1 ? wk : wv;
  const float* bias = which == 0 ? bq : which == 1 ? bk : bv;

  __shared__ f16 As[2][128 * 32];
  __shared__ f16 Bs[2][64 * 32];

  const f16* a0 = A + (size_t)(bm + (t >> 2)) * K + (t & 3) * 8;
  const f16* a1 = a0 + (size_t)64 * K;
  const f16* b0 = Bw + (size_t)(bn + (t >> 2)) * K + (t & 3) * 8;

  f32x4 acc[2][4];
#pragma unroll
  for (int m = 0; m < 2; ++m)
#pragma unroll
    for (int n = 0; n < 4; ++n) acc[m][n] = (f32x4){0.f, 0.f, 0.f, 0.f};

#define STAGE_G(buf, k0)                          \
  do {                                            \
    gload16(a0 + (k0), &As[buf][w * 512]);        \
    gload16(a1 + (k0), &As[buf][2048 + w * 512]); \
    gload16(b0 + (k0), &Bs[buf][w * 512]);        \
  } while (0)

  STAGE_G(0, 0);
  __syncthreads();
  int cur = 0;
#pragma unroll 1
  for (int kt = 0; kt < 32; ++kt) {
    if (kt < 31) STAGE_G(cur ^ 1, (kt + 1) * 32);
    const f16* ap = &As[cur][(w * 32 + l15) * 32 + l4 * 8];
    const f16* bp = &Bs[cur][l15 * 32 + l4 * 8];
    f16x8 af[2], bfr[4];
#pragma unroll
    for (int m = 0; m < 2; ++m) af[m] = *(const f16x8*)(ap + m * 512);
#pragma unroll
    for (int n = 0; n < 4; ++n) bfr[n] = *(const f16x8*)(bp + n * 512);
#pragma unroll
    for (int m = 0; m < 2; ++m)
#pragma unroll
      for (int n = 0; n < 4; ++n)
        acc[m][n] = __builtin_amdgcn_mfma_f32_16x16x32_f16(af[m], bfr[n], acc[m][n], 0, 0, 0);
    __syncthreads();
    cur ^= 1;
  }
#undef STAGE_G

  const float scale = which == 0 ? 0.125f * LOG2E : 1.0f;
  f16* outp = which == 0 ? Qp : which == 1 ? Kp : Vt;
#pragma unroll
  for (int m = 0; m < 2; ++m) {
    const int r0 = bm + w * 32 + m * 16 + (l4 << 2);
#pragma unroll
    for (int n = 0; n < 4; ++n) {
      const int c = bn + n * 16 + l15;
      const float bv = bias[c];
#pragma unroll
      for (int j = 0; j < 4; ++j) {
        const int r = r0 + j;
        const float v = (acc[m][n][j] + bv) * scale;
        const int b_ = r >> 11, s = r & 2047, h_ = c >> 6, dk = c & 63;
        if (which < 2)
          outp[(((size_t)b_ * 16 + h_) * 2048 + s) * 64 + dk] = (f16)v;
        else
          outp[(((size_t)b_ * 16 + h_) * 64 + dk) * 2048 + s] = (f16)v;
      }
    }
  }
}

// ---------------- output projection GEMM (f32 out) -------------------------
__global__ __launch_bounds__(256, 2) void gemm_out(const f16* __restrict__ A,
                                                   const f16* __restrict__ Bw,
                                                   const float* __restrict__ bias,
                                                   float* __restrict__ outp) {
  constexpr int K = 1024;
  const int t = threadIdx.x;
  const int w = t >> 6, lane = t & 63, l15 = lane & 15, l4 = lane >> 4;
  const int bm = (int)(blockIdx.x >> 4) * 128;
  const int bn = (int)(blockIdx.x & 15) * 64;

  __shared__ f16 As[2][128 * 32];
  __shared__ f16 Bs[2][64 * 32];

  const f16* a0 = A + (size_t)(bm + (t >> 2)) * K + (t & 3) * 8;
  const f16* a1 = a0 + (size_t)64 * K;
  const f16* b0 = Bw + (size_t)(bn + (t >> 2)) * K + (t & 3) * 8;

  f32x4 acc[2][4];
#pragma unroll
  for (int m = 0; m < 2; ++m)
#pragma unroll
    for (int n = 0; n < 4; ++n) acc[m][n] = (f32x4){0.f, 0.f, 0.f, 0.f};

#define STAGE_G(buf, k0)                          \
  do {                                            \
    gload16(a0 + (k0), &As[buf][w * 512]);        \
    gload16(a1 + (k0), &As[buf][2048 + w * 512]); \
    gload16(b0 + (k0), &Bs[buf][w * 512]);        \
  } while (0)

  STAGE_G(0, 0);
  __syncthreads();
  int cur = 0;
#pragma unroll 1
  for (int kt = 0; kt < 32; ++kt) {
    if (kt < 31) STAGE_G(cur ^ 1, (kt + 1) * 32);
    const f16* ap = &As[cur][(w * 32 + l15) * 32 + l4 * 8];
    const f16* bp = &Bs[cur][l15 * 32 + l4 * 8];
    f16x8 af[2], bfr[4];
#pragma unroll
    for (int m = 0; m < 2; ++m) af[m] = *(const f16x8*)(ap + m * 512);
#pragma unroll
    for (int n = 0; n < 4; ++n) bfr[n] = *(const f16x8*)(bp + n * 512);
#pragma unroll
    for (int m = 0; m < 2; ++m)
#pragma unroll
      for (int n = 0; n < 4; ++n)
        acc[m][n] = __builtin_amdgcn_mfma_f32_16x16x32_f16(af[m], bfr[n], acc[m][n], 0, 0, 0);
    __syncthreads();
    cur ^= 1;
  }
#undef STAGE_G

#pragma unroll
  for (int m = 0; m < 2; ++m) {
    const int r0 = bm + w * 32 + m * 16 + (l4 << 2);
#pragma unroll
    for (int n = 0; n < 4; ++n) {
      const int c = bn + n * 16 + l15;
      const float bv = bias[c];
#pragma unroll
      for (int j = 0; j < 4; ++j)
        outp[(size_t)(r0 + j) * 1024 + c] = acc[m][n][j] + bv;
    }
  }
}

// ---------------- batch-merged zero-barrier flash attention ----------------
// 512 blocks: bid -> (qt 0..31, h 0..15). K+V (17MB) are L2-resident: each
// wave loads its K/V MFMA fragments directly global->regs (16B contiguous,
// same pattern as Q-frags). No LDS staging, NO barriers — waves decouple,
// loads pipeline freely. Only LDS use: per-wave P roundtrip (lgkm only).
// Bias/mask prefetched one kv-tile ahead (static double-buffered reg sets).
__global__ __launch_bounds__(256, 2) void attn_fwd(
    const f16* __restrict__ Qp, const f16* __restrict__ Kp,
    const f16* __restrict__ Vt, const float* __restrict__ bias,
    const uint8_t* __restrict__ mask, f16* __restrict__ X) {
  constexpr int S = 2048;
  const int bid = blockIdx.x;
  const int qt = bid & 31, h = bid >> 5;
  const int t = threadIdx.x, w = t >> 6, lane = t & 63;
  const int l15 = lane & 15, l4 = lane >> 4;
  const int q0 = qt * 64 + w * 16;

  const f16* Qb[2] = {Qp + (size_t)h * S * 64, Qp + (size_t)(16 + h) * S * 64};
  // per-lane fragment bases: K rows l15-strided, 16B chunk l4
  const f16* kf0 = Kp + (size_t)h * S * 64 + (size_t)l15 * 64 + l4 * 8;
  const f16* kf1 = kf0 + (size_t)16 * S * 64;
  const f16* vf0 = Vt + (size_t)h * 64 * S + (size_t)l15 * S + l4 * 8;
  const f16* vf1 = vf0 + (size_t)16 * 64 * S;
  const float* biasr = bias + (size_t)h * S * S + (size_t)(q0 + l15) * S + l4 * 4;
  const uint8_t* mr0 = mask + (size_t)(q0 + l15) * S + l4 * 4;
  const uint8_t* mr1 = mr0 + (size_t)S * S;

  __shared__ f16 Ps[4][16 * 64];  // per-wave P, swizzled (lgkm-only roundtrip)

  // Q B-frags for both batches (Q pre-scaled by 0.125*log2e)
  f16x8 qf[2][2];
#pragma unroll
  for (int bb = 0; bb < 2; ++bb)
#pragma unroll
    for (int ks = 0; ks < 2; ++ks)
      qf[bb][ks] =
          *(const f16x8*)(Qb[bb] + (size_t)(q0 + l15) * 64 + ks * 32 + l4 * 8);

  f32x4 oacc[2][4];
#pragma unroll
  for (int bb = 0; bb < 2; ++bb)
#pragma unroll
    for (int n = 0; n < 4; ++n) oacc[bb][n] = (f32x4){0.f, 0.f, 0.f, 0.f};
  float mrow[2] = {-3e38f, -3e38f}, lrow[2] = {0.f, 0.f};

  // bias/mask static double-buffer
  f32x4 bcA[4], bcB[4];
  uint32_t mcA[2][4], mcB[2][4];

#define LOADB(BC, MC, kk)                                   \
  do {                                                      \
    _Pragma("unroll") for (int n = 0; n < 4; ++n) {         \
      BC[n] = *(const f32x4*)(biasr + (kk) + n * 16);       \
      MC[0][n] = *(const uint32_t*)(mr0 + (kk) + n * 16);   \
      MC[1][n] = *(const uint32_t*)(mr1 + (kk) + n * 16);   \
    }                                                       \
  } while (0)

// one kv-tile (64 k): prefetch next tile's bias/mask, K-frags->QK MFMA,
// softmax in-register, P via per-wave LDS, V-frags->PV MFMA. No barriers.
#define TILE(BC, MC, BCN, MCN, k0)                                                       \
  do {                                                                                   \
    LOADB(BCN, MCN, ((k0) + 64) & (S - 1));                                              \
    f32x4 sacc[2][4];                                                                    \
    _Pragma("unroll") for (int bb = 0; bb < 2; ++bb)                                     \
      _Pragma("unroll") for (int n = 0; n < 4; ++n)                                      \
        sacc[bb][n] = (f32x4){0.f, 0.f, 0.f, 0.f};                                       \
    _Pragma("unroll") for (int n = 0; n < 4; ++n)                                        \
      _Pragma("unroll") for (int ks = 0; ks < 2; ++ks) {                                 \
        const f16x8 k0f = *(const f16x8*)(kf0 + (size_t)((k0) + n * 16) * 64 + ks * 32); \
        const f16x8 k1f = *(const f16x8*)(kf1 + (size_t)((k0) + n * 16) * 64 + ks * 32); \
        sacc[0][n] = __builtin_amdgcn_mfma_f32_16x16x32_f16(k0f, qf[0][ks],              \
                                                            sacc[0][n], 0, 0, 0);        \
        sacc[1][n] = __builtin_amdgcn_mfma_f32_16x16x32_f16(k1f, qf[1][ks],              \
                                                            sacc[1][n], 0, 0, 0);        \
      }                                                                                  \
    _Pragma("unroll") for (int bb = 0; bb < 2; ++bb) {                                   \
      float tmax = -3e38f;                                                               \
      _Pragma("unroll") for (int n = 0; n < 4; ++n) {                                    \
        _Pragma("unroll") for (int j = 0; j < 4; ++j) {                                  \
          const float mf = (float)((MC[bb][n] >> (8 * j)) & 255u);                       \
          sacc[bb][n][j] = fmaf(mf, -2e9f, fmaf(BC[n][j], LOG2E, sacc[bb][n][j]));       \
        }                                                                                \
        tmax = fmaxf(tmax, fmaxf(fmaxf(sacc[bb][n][0], sacc[bb][n][1]),                  \
                                 fmaxf(sacc[bb][n][2], sacc[bb][n][3])));                \
      }                                                                                  \
      tmax = fmaxf(tmax, __shfl_xor(tmax, 16));                                          \
      tmax = fmaxf(tmax, __shfl_xor(tmax, 32));                                          \
      const float mnew = fmaxf(mrow[bb], tmax);                                          \
      const float alpha = __builtin_exp2f(mrow[bb] - mnew);                              \
      mrow[bb] = mnew;                                                                   \
      float lsum = 0.f;                                                                  \
      _Pragma("unroll") for (int n = 0; n < 4; ++n)                                      \
        _Pragma("unroll") for (int j = 0; j < 4; ++j) {                                  \
          const float e = __builtin_exp2f(sacc[bb][n][j] - mnew);                        \
          sacc[bb][n][j] = e;                                                            \
          lsum += e;                                                                     \
        }                                                                                \
      lsum += __shfl_xor(lsum, 16);                                                      \
      lsum += __shfl_xor(lsum, 32);                                                      \
      lrow[bb] = lrow[bb] * alpha + lsum;                                                \
      float aq[4];                                                                       \
      _Pragma("unroll") for (int j = 0; j < 4; ++j) aq[j] = __shfl(alpha, l4 * 4 + j);   \
      _Pragma("unroll") for (int n = 0; n < 4; ++n)                                      \
        _Pragma("unroll") for (int j = 0; j < 4; ++j) oacc[bb][n][j] *= aq[j];           \
      _Pragma("unroll") for (int n = 0; n < 4; ++n) {                                    \
        h2 p01 = __builtin_amdgcn_cvt_pkrtz(sacc[bb][n][0], sacc[bb][n][1]);             \
        h2 p23 = __builtin_amdgcn_cvt_pkrtz(sacc[bb][n][2], sacc[bb][n][3]);             \
        f16x4 pk;                                                                        \
        pk[0] = (f16)p01[0]; pk[1] = (f16)p01[1];                                        \
        pk[2] = (f16)p23[0]; pk[3] = (f16)p23[1];                                        \
        *(f16x4*)((char*)&Ps[w][0] + l15 * 128 +                                         \
                  ((32 * n + 8 * l4) ^ ((l15 & 7) << 4))) = pk;                          \
      }                                                                                  \
      f16x8 pf[2];                                                                       \
      _Pragma("unroll") for (int ks = 0; ks < 2; ++ks)                                   \
        pf[ks] = *(const f16x8*)((const char*)&Ps[w][0] + l15 * 128 +                    \
                                 ((ks * 64 + l4 * 16) ^ ((l15 & 7) << 4)));              \
      const f16* vfb = (bb == 0) ? vf0 : vf1;                                            \
      _Pragma("unroll") for (int ks = 0; ks < 2; ++ks)                                   \
        _Pragma("unroll") for (int n = 0; n < 4; ++n) {                                  \
          const f16x8 vf =                                                               \
              *(const f16x8*)(vfb + (size_t)n * 16 * S + (k0) + ks * 32);                \
          oacc[bb][n] = __builtin_amdgcn_mfma_f32_16x16x32_f16(pf[ks], vf,               \
                                                               oacc[bb][n], 0, 0, 0);    \
        }                                                                                \
    }                                                                                    \
  } while (0)

  // prologue: tile 0's bias/mask
  LOADB(bcA, mcA, 0);

#pragma unroll 1
  for (int kt = 0; kt < 32; kt += 2) {
    TILE(bcA, mcA, bcB, mcB, kt * 64);        // uses A, prefetches B (kt+1)
    TILE(bcB, mcB, bcA, mcA, (kt + 1) * 64);  // uses B, prefetches A (kt+2)
  }
#undef TILE
#undef LOADB

  // ---- normalize and store X[b,s,h*64+d] (f16) ----
#pragma unroll
  for (int bb = 0; bb < 2; ++bb) {
    const float inv = 1.0f / lrow[bb];
    float invq[4];
#pragma unroll
    for (int j = 0; j < 4; ++j) invq[j] = __shfl(inv, l4 * 4 + j);
#pragma unroll
    for (int j = 0; j < 4; ++j) {
      const int qrow = q0 + l4 * 4 + j;
#pragma unroll
      for (int n = 0; n < 4; ++n)
        X[((size_t)bb * 2048 + qrow) * 1024 + h * 64 + n * 16 + l15] =
            (f16)(oacc[bb][n][j] * invq[j]);
    }
  }
}

// ---------------- host ------------------------------------------------------
extern "C" void kernel_launch(void* const* d_in, const int* in_sizes, int n_in,
                              void* d_out, int out_size, void* d_ws, size_t ws_size,
                              hipStream_t stream) {
  const float* query = (const float*)d_in[0];
  const float* key_ = (const float*)d_in[1];
  const float* value = (const float*)d_in[2];
  const uint8_t* mask = (const uint8_t*)d_in[3];
  const float* bias = (const float*)d_in[4];
  const float* Wq = (const float*)d_in[5];
  const float* bq = (const float*)d_in[6];
  const float* Wk = (const float*)d_in[7];
  const float* bk = (const float*)d_in[8];
  const float* Wv = (const float*)d_in[9];
  const float* bv = (const float*)d_in[10];
  const float* Wo = (const float*)d_in[11];
  const float* bo = (const float*)d_in[12];

  char* p = (char*)d_ws;
  f16* qh = (f16*)p; p += (size_t)4194304 * 2;   // contiguous cvt dst region:
  f16* kh = (f16*)p; p += (size_t)4194304 * 2;   // qh,kh,vh,wqh,wkh,wvh,woh
  f16* vh = (f16*)p; p += (size_t)4194304 * 2;
  f16* wqh = (f16*)p; p += (size_t)1048576 * 2;
  f16* wkh = (f16*)p; p += (size_t)1048576 * 2;
  f16* wvh = (f16*)p; p += (size_t)1048576 * 2;
  f16* woh = (f16*)p; p += (size_t)1048576 * 2;
  f16* Qp = (f16*)p; p += (size_t)4194304 * 2;
  f16* Kp = (f16*)p; p += (size_t)4194304 * 2;
  f16* Vt = (f16*)p; p += (size_t)4194304 * 2;
  f16* Xh = (f16*)p; p += (size_t)4194304 * 2;
  uint8_t* m8 = (uint8_t*)p; p += (size_t)8388608;
  int* flag = (int*)p; p += 256;
  if (ws_size < (size_t)(p - (char*)d_ws)) return;

  mask_detect<<<1, 256, 0, stream>>>(mask, flag);
  mask_canon<<<8192, 256, 0, stream>>>(mask, m8, flag);

  CvtSrcs cs;
  cs.s[0] = query; cs.s[1] = key_; cs.s[2] = value;
  cs.s[3] = Wq; cs.s[4] = Wk; cs.s[5] = Wv; cs.s[6] = Wo;
  cvt_all<<<16384, 256, 0, stream>>>(cs, qh);

  gemm_qkv<<<1536, 256, 0, stream>>>(qh, kh, vh, wqh, wkh, wvh, bq, bk, bv,
                                     Qp, Kp, Vt);

  attn_fwd<<<512, 256, 0, stream>>>(Qp, Kp, Vt, bias, m8, Xh);

  gemm_out<<<512, 256, 0, stream>>>(Xh, woh, bo, (float*)d_out);
}

// Round 10
// 258.025 us; speedup vs baseline: 1.8140x; 1.8140x over previous
//
#include <hip/hip_runtime.h>
#include <stdint.h>

// MultiHeadedAttention: B=2,S=2048,D=1024,H=16,DK=64
// Pipeline: fused f32->f16 cvt; fused QKV proj GEMM (MFMA f16, Q pre-scaled
// by 0.125*log2e); batch-merged flash attention with issue-early/1-barrier
// tiles (K/V dbuf LDS; ALL of tile kt+1's loads issued before tile kt's
// compute -> full compute phase of flight; single __syncthreads per tile);
// out proj GEMM -> f32.

typedef _Float16 f16;
typedef _Float16 f16x8 __attribute__((ext_vector_type(8)));
typedef _Float16 f16x4 __attribute__((ext_vector_type(4)));
typedef __fp16 h2 __attribute__((ext_vector_type(2)));
typedef float f32x4 __attribute__((ext_vector_type(4)));

#define LOG2E 1.44269504088896340736f

__device__ __forceinline__ void gload16(const void* g, void* l) {
  __builtin_amdgcn_global_load_lds(
      (const __attribute__((address_space(1))) unsigned int*)g,
      (__attribute__((address_space(3))) unsigned int*)l, 16, 0, 0);
}

// ---------------- fused f32 -> f16 conversion ------------------------------
struct CvtSrcs { const float* s[7]; };

__global__ __launch_bounds__(256) void cvt_all(CvtSrcs a, f16* __restrict__ out) {
  const int i = blockIdx.x * 256 + threadIdx.x;  // 0 .. 4194303
  int r, base;
  if (i < 3145728) { r = i >> 20; base = r << 20; }
  else { r = 3 + ((i - 3145728) >> 18); base = 3145728 + ((r - 3) << 18); }
  const float4 v = ((const float4*)a.s[r])[i - base];
  f16x4 o = {(f16)v.x, (f16)v.y, (f16)v.z, (f16)v.w};
  ((f16x4*)out)[i] = o;
}

// ---------------- mask dtype classify + canonicalize to u8 ----------------
__global__ void mask_detect(const uint8_t* __restrict__ m, int* __restrict__ flag) {
  __shared__ int s_off, s_weird;
  const int t = threadIdx.x;
  if (t == 0) { s_off = 0; s_weird = 0; }
  __syncthreads();
  int f_off = 0, f_weird = 0;
  for (int i = t; i < 8192; i += 256) {
    const uint8_t v = m[i];
    if ((i & 3) && v) f_off = 1;
    if (v > 1) f_weird = 1;
  }
  if (f_off) atomicOr(&s_off, 1);
  if (f_weird) atomicOr(&s_weird, 1);
  __syncthreads();
  if (t == 0) *flag = (s_off && !s_weird) ? 1 : 0;  // 1 => byte-sized bool
}

__global__ __launch_bounds__(256) void mask_canon(const uint8_t* __restrict__ m,
                                                  uint8_t* __restrict__ out,
                                                  const int* __restrict__ flag) {
  const int i = (blockIdx.x * 256 + threadIdx.x) * 4;  // grid covers 8388608
  uchar4 o;
  if (*flag) {
    const uchar4 v = *(const uchar4*)(m + i);
    o = make_uchar4(v.x != 0, v.y != 0, v.z != 0, v.w != 0);
  } else {
    const int4 v = *(const int4*)((const int*)m + i);
    o = make_uchar4(v.x != 0, v.y != 0, v.z != 0, v.w != 0);
  }
  *(uchar4*)(out + i) = o;
}

// ---------------- fused QKV projection GEMM --------------------------------
__global__ __launch_bounds__(256, 2) void gemm_qkv(
    const f16* __restrict__ qh, const f16* __restrict__ kh, const f16* __restrict__ vh,
    const f16* __restrict__ wq, const f16* __restrict__ wk, const f16* __restrict__ wv,
    const float* __restrict__ bq, const float* __restrict__ bk, const float* __restrict__ bv,
    f16* __restrict__ Qp, f16* __restrict__ Kp, f16* __restrict__ Vt) {
  constexpr int K = 1024;
  const int t = threadIdx.x;
  const int w = t >> 6, lane = t & 63, l15 = lane & 15, l4 = lane >> 4;
  const int nt = (int)blockIdx.x % 48;
  const int bm = ((int)blockIdx.x / 48) * 128;
  const int which = nt >> 4;
  const int bn = (nt & 15) * 64;
  const f16* A = which == 0 ? qh : which == 1 ? kh : vh;
  const f16* Bw = which == 0 ? wq : which == 1 ? wk : wv;
  const float* bias = which == 0 ? bq : which == 1 ? bk : bv;

  __shared__ f16 As[2][128 * 32];
  __shared__ f16 Bs[2][64 * 32];

  const f16* a0 = A + (size_t)(bm + (t >> 2)) * K + (t & 3) * 8;
  const f16* a1 = a0 + (size_t)64 * K;
  const f16* b0 = Bw + (size_t)(bn + (t >> 2)) * K + (t & 3) * 8;

  f32x4 acc[2][4];
#pragma unroll
  for (int m = 0; m < 2; ++m)
#pragma unroll
    for (int n = 0; n < 4; ++n) acc[m][n] = (f32x4){0.f, 0.f, 0.f, 0.f};

#define STAGE_G(buf, k0)                          \
  do {                                            \
    gload16(a0 + (k0), &As[buf][w * 512]);        \
    gload16(a1 + (k0), &As[buf][2048 + w * 512]); \
    gload16(b0 + (k0), &Bs[buf][w * 512]);        \
  } while (0)

  STAGE_G(0, 0);
  __syncthreads();
  int cur = 0;
#pragma unroll 1
  for (int kt = 0; kt < 32; ++kt) {
    if (kt < 31) STAGE_G(cur ^ 1, (kt + 1) * 32);
    const f16* ap = &As[cur][(w * 32 + l15) * 32 + l4 * 8];
    const f16* bp = &Bs[cur][l15 * 32 + l4 * 8];
    f16x8 af[2], bfr[4];
#pragma unroll
    for (int m = 0; m < 2; ++m) af[m] = *(const f16x8*)(ap + m * 512);
#pragma unroll
    for (int n = 0; n < 4; ++n) bfr[n] = *(const f16x8*)(bp + n * 512);
#pragma unroll
    for (int m = 0; m < 2; ++m)
#pragma unroll
      for (int n = 0; n < 4; ++n)
        acc[m][n] = __builtin_amdgcn_mfma_f32_16x16x32_f16(af[m], bfr[n], acc[m][n], 0, 0, 0);
    __syncthreads();
    cur ^= 1;
  }
#undef STAGE_G

  const float scale = which == 0 ? 0.125f * LOG2E : 1.0f;
  f16* outp = which == 0 ? Qp : which == 1 ? Kp : Vt;
#pragma unroll
  for (int m = 0; m < 2; ++m) {
    const int r0 = bm + w * 32 + m * 16 + (l4 << 2);
#pragma unroll
    for (int n = 0; n < 4; ++n) {
      const int c = bn + n * 16 + l15;
      const float bv = bias[c];
#pragma unroll
      for (int j = 0; j < 4; ++j) {
        const int r = r0 + j;
        const float v = (acc[m][n][j] + bv) * scale;
        const int b_ = r >> 11, s = r & 2047, h_ = c >> 6, dk = c & 63;
        if (which < 2)
          outp[(((size_t)b_ * 16 + h_) * 2048 + s) * 64 + dk] = (f16)v;
        else
          outp[(((size_t)b_ * 16 + h_) * 64 + dk) * 2048 + s] = (f16)v;
      }
    }
  }
}

// ---------------- output projection GEMM (f32 out) -------------------------
__global__ __launch_bounds__(256, 2) void gemm_out(const f16* __restrict__ A,
                                                   const f16* __restrict__ Bw,
                                                   const float* __restrict__ bias,
                                                   float* __restrict__ outp) {
  constexpr int K = 1024;
  const int t = threadIdx.x;
  const int w = t >> 6, lane = t & 63, l15 = lane & 15, l4 = lane >> 4;
  const int bm = (int)(blockIdx.x >> 4) * 128;
  const int bn = (int)(blockIdx.x & 15) * 64;

  __shared__ f16 As[2][128 * 32];
  __shared__ f16 Bs[2][64 * 32];

  const f16* a0 = A + (size_t)(bm + (t >> 2)) * K + (t & 3) * 8;
  const f16* a1 = a0 + (size_t)64 * K;
  const f16* b0 = Bw + (size_t)(bn + (t >> 2)) * K + (t & 3) * 8;

  f32x4 acc[2][4];
#pragma unroll
  for (int m = 0; m < 2; ++m)
#pragma unroll
    for (int n = 0; n < 4; ++n) acc[m][n] = (f32x4){0.f, 0.f, 0.f, 0.f};

#define STAGE_G(buf, k0)                          \
  do {                                            \
    gload16(a0 + (k0), &As[buf][w * 512]);        \
    gload16(a1 + (k0), &As[buf][2048 + w * 512]); \
    gload16(b0 + (k0), &Bs[buf][w * 512]);        \
  } while (0)

  STAGE_G(0, 0);
  __syncthreads();
  int cur = 0;
#pragma unroll 1
  for (int kt = 0; kt < 32; ++kt) {
    if (kt < 31) STAGE_G(cur ^ 1, (kt + 1) * 32);
    const f16* ap = &As[cur][(w * 32 + l15) * 32 + l4 * 8];
    const f16* bp = &Bs[cur][l15 * 32 + l4 * 8];
    f16x8 af[2], bfr[4];
#pragma unroll
    for (int m = 0; m < 2; ++m) af[m] = *(const f16x8*)(ap + m * 512);
#pragma unroll
    for (int n = 0; n < 4; ++n) bfr[n] = *(const f16x8*)(bp + n * 512);
#pragma unroll
    for (int m = 0; m < 2; ++m)
#pragma unroll
      for (int n = 0; n < 4; ++n)
        acc[m][n] = __builtin_amdgcn_mfma_f32_16x16x32_f16(af[m], bfr[n], acc[m][n], 0, 0, 0);
    __syncthreads();
    cur ^= 1;
  }
#undef STAGE_G

#pragma unroll
  for (int m = 0; m < 2; ++m) {
    const int r0 = bm + w * 32 + m * 16 + (l4 << 2);
#pragma unroll
    for (int n = 0; n < 4; ++n) {
      const int c = bn + n * 16 + l15;
      const float bv = bias[c];
#pragma unroll
      for (int j = 0; j < 4; ++j)
        outp[(size_t)(r0 + j) * 1024 + c] = acc[m][n][j] + bv;
    }
  }
}

// ---------------- batch-merged flash attention, issue-early tiles ----------
// 512 blocks: bid -> (qt, h). Per tile: issue ALL of tile kt+1's loads
// (K/V gload_lds into the other buffer + bias/mask into the other reg set)
// FIRST, then compute tile kt, then one __syncthreads (drains everything:
// next tile fully ready, this buffer free). Every load gets a full compute
// phase (~2-3K cyc) of flight instead of ~0. Running pointers with imm-
// folded offsets keep address VALU minimal.
__device__ __forceinline__ const f16x8* swzr(const f16* base, int row, int bytecol) {
  return (const f16x8*)((const char*)base + row * 128 + (bytecol ^ ((row & 7) << 4)));
}

__global__ __launch_bounds__(256, 2) void attn_fwd(
    const f16* __restrict__ Qp, const f16* __restrict__ Kp,
    const f16* __restrict__ Vt, const float* __restrict__ bias,
    const uint8_t* __restrict__ mask, f16* __restrict__ X) {
  constexpr int S = 2048;
  const int bid = blockIdx.x;
  const int qt = bid & 31, h = bid >> 5;
  const int t = threadIdx.x, w = t >> 6, lane = t & 63;
  const int l15 = lane & 15, l4 = lane >> 4;
  const int q0 = qt * 64 + w * 16;

  const f16* Qb0 = Qp + (size_t)h * S * 64;
  const f16* Qb1 = Qp + (size_t)(16 + h) * S * 64;

  __shared__ f16 Ks[2][2][64 * 64];  // [buf][batch][kv][dk], swizzled
  __shared__ f16 Vs[2][2][64 * 64];  // [buf][batch][dk][kv], swizzled
  __shared__ f16 Ps[4][16 * 64];     // per-wave P, swizzled

  // Q B-frags (Q pre-scaled by 0.125*log2e)
  f16x8 qf[2][2];
#pragma unroll
  for (int ks = 0; ks < 2; ++ks) {
    qf[0][ks] = *(const f16x8*)(Qb0 + (size_t)(q0 + l15) * 64 + ks * 32 + l4 * 8);
    qf[1][ks] = *(const f16x8*)(Qb1 + (size_t)(q0 + l15) * 64 + ks * 32 + l4 * 8);
  }

  f32x4 oacc[2][4];
#pragma unroll
  for (int bb = 0; bb < 2; ++bb)
#pragma unroll
    for (int n = 0; n < 4; ++n) oacc[bb][n] = (f32x4){0.f, 0.f, 0.f, 0.f};
  float mrow[2] = {-3e38f, -3e38f}, lrow[2] = {0.f, 0.f};

  // running per-lane source pointers (advanced once per staged tile)
  const int srow = t >> 3;
  const int scol = (((t & 7) ^ (srow & 7)) << 3);
  const f16* kp0 = Kp + (size_t)h * S * 64 + (size_t)srow * 64 + scol;
  const f16* kp1 = kp0 + (size_t)16 * S * 64;
  const f16* vp0 = Vt + (size_t)h * 64 * S + (size_t)srow * S + scol;
  const f16* vp1 = vp0 + (size_t)16 * 64 * S;
  const float* bp = bias + (size_t)h * S * S + (size_t)(q0 + l15) * S + l4 * 4;
  const uint8_t* mp0 = mask + (size_t)(q0 + l15) * S + l4 * 4;
  const uint8_t* mp1 = mp0 + (size_t)S * S;

  f32x4 bcA[4], bcB[4];
  uint32_t mcA[2][4], mcB[2][4];

#define STAGE(BUF)                                              \
  do {                                                          \
    gload16(kp0, &Ks[BUF][0][w * 512]);                         \
    gload16(kp0 + 2048, &Ks[BUF][0][2048 + w * 512]);           \
    gload16(kp1, &Ks[BUF][1][w * 512]);                         \
    gload16(kp1 + 2048, &Ks[BUF][1][2048 + w * 512]);           \
    gload16(vp0, &Vs[BUF][0][w * 512]);                         \
    gload16(vp0 + 32 * S, &Vs[BUF][0][2048 + w * 512]);         \
    gload16(vp1, &Vs[BUF][1][w * 512]);                         \
    gload16(vp1 + 32 * S, &Vs[BUF][1][2048 + w * 512]);         \
    kp0 += 4096; kp1 += 4096; vp0 += 64; vp1 += 64;             \
  } while (0)

#define LOADB(BC, MC)                                \
  do {                                               \
    BC[0] = *(const f32x4*)(bp);                     \
    BC[1] = *(const f32x4*)(bp + 16);                \
    BC[2] = *(const f32x4*)(bp + 32);                \
    BC[3] = *(const f32x4*)(bp + 48);                \
    MC[0][0] = *(const uint32_t*)(mp0);              \
    MC[0][1] = *(const uint32_t*)(mp0 + 16);         \
    MC[0][2] = *(const uint32_t*)(mp0 + 32);         \
    MC[0][3] = *(const uint32_t*)(mp0 + 48);         \
    MC[1][0] = *(const uint32_t*)(mp1);              \
    MC[1][1] = *(const uint32_t*)(mp1 + 16);         \
    MC[1][2] = *(const uint32_t*)(mp1 + 32);         \
    MC[1][3] = *(const uint32_t*)(mp1 + 48);         \
    bp += 64; mp0 += 64; mp1 += 64;                  \
  } while (0)

#define COMPUTE(BUF, BC, MC)                                                             \
  do {                                                                                   \
    f32x4 sacc[2][4];                                                                    \
    _Pragma("unroll") for (int bb = 0; bb < 2; ++bb)                                     \
      _Pragma("unroll") for (int n = 0; n < 4; ++n)                                      \
        sacc[bb][n] = (f32x4){0.f, 0.f, 0.f, 0.f};                                       \
    _Pragma("unroll") for (int bb = 0; bb < 2; ++bb)                                     \
      _Pragma("unroll") for (int n = 0; n < 4; ++n)                                      \
        _Pragma("unroll") for (int ks = 0; ks < 2; ++ks) {                               \
          const f16x8 kf = *swzr(&Ks[BUF][bb][0], n * 16 + l15, ks * 64 + l4 * 16);      \
          sacc[bb][n] = __builtin_amdgcn_mfma_f32_16x16x32_f16(kf, qf[bb][ks],           \
                                                               sacc[bb][n], 0, 0, 0);    \
        }                                                                                \
    _Pragma("unroll") for (int bb = 0; bb < 2; ++bb) {                                   \
      float tmax = -3e38f;                                                               \
      _Pragma("unroll") for (int n = 0; n < 4; ++n) {                                    \
        _Pragma("unroll") for (int j = 0; j < 4; ++j) {                                  \
          const float mf = (float)((MC[bb][n] >> (8 * j)) & 255u);                       \
          sacc[bb][n][j] = fmaf(mf, -2e9f, fmaf(BC[n][j], LOG2E, sacc[bb][n][j]));       \
        }                                                                                \
        tmax = fmaxf(tmax, fmaxf(fmaxf(sacc[bb][n][0], sacc[bb][n][1]),                  \
                                 fmaxf(sacc[bb][n][2], sacc[bb][n][3])));                \
      }                                                                                  \
      tmax = fmaxf(tmax, __shfl_xor(tmax, 16));                                          \
      tmax = fmaxf(tmax, __shfl_xor(tmax, 32));                                          \
      const float mnew = fmaxf(mrow[bb], tmax);                                          \
      const float alpha = __builtin_exp2f(mrow[bb] - mnew);                              \
      mrow[bb] = mnew;                                                                   \
      float lsum = 0.f;                                                                  \
      _Pragma("unroll") for (int n = 0; n < 4; ++n)                                      \
        _Pragma("unroll") for (int j = 0; j < 4; ++j) {                                  \
          const float e = __builtin_exp2f(sacc[bb][n][j] - mnew);                        \
          sacc[bb][n][j] = e;                                                            \
          lsum += e;                                                                     \
        }                                                                                \
      lsum += __shfl_xor(lsum, 16);                                                      \
      lsum += __shfl_xor(lsum, 32);                                                      \
      lrow[bb] = lrow[bb] * alpha + lsum;                                                \
      float aq[4];                                                                       \
      _Pragma("unroll") for (int j = 0; j < 4; ++j) aq[j] = __shfl(alpha, l4 * 4 + j);   \
      _Pragma("unroll") for (int n = 0; n < 4; ++n)                                      \
        _Pragma("unroll") for (int j = 0; j < 4; ++j) oacc[bb][n][j] *= aq[j];           \
      _Pragma("unroll") for (int n = 0; n < 4; ++n) {                                    \
        const h2 p01 = __builtin_amdgcn_cvt_pkrtz(sacc[bb][n][0], sacc[bb][n][1]);       \
        const h2 p23 = __builtin_amdgcn_cvt_pkrtz(sacc[bb][n][2], sacc[bb][n][3]);       \
        uint2 pk;                                                                        \
        pk.x = __builtin_bit_cast(unsigned int, p01);                                    \
        pk.y = __builtin_bit_cast(unsigned int, p23);                                    \
        *(uint2*)((char*)&Ps[w][0] + l15 * 128 +                                         \
                  ((32 * n + 8 * l4) ^ ((l15 & 7) << 4))) = pk;                          \
      }                                                                                  \
      f16x8 pf[2];                                                                       \
      _Pragma("unroll") for (int ks = 0; ks < 2; ++ks)                                   \
        pf[ks] = *swzr(&Ps[w][0], l15, ks * 64 + l4 * 16);                               \
      _Pragma("unroll") for (int ks = 0; ks < 2; ++ks)                                   \
        _Pragma("unroll") for (int n = 0; n < 4; ++n) {                                  \
          const f16x8 vf = *swzr(&Vs[BUF][bb][0], n * 16 + l15, ks * 64 + l4 * 16);      \
          oacc[bb][n] = __builtin_amdgcn_mfma_f32_16x16x32_f16(pf[ks], vf,               \
                                                               oacc[bb][n], 0, 0, 0);    \
        }                                                                                \
    }                                                                                    \
  } while (0)

  // prologue: tile 0's loads, drained by first barrier
  STAGE(0);
  LOADB(bcA, mcA);
  __syncthreads();

#pragma unroll 1
  for (int kt = 0; kt < 32; kt += 2) {
    // even tile (buf0, regs A): issue tile kt+1 first, then compute
    STAGE(1);
    LOADB(bcB, mcB);
    COMPUTE(0, bcA, mcA);
    __syncthreads();  // tile kt+1 staged+loaded; buf0 free
    // odd tile (buf1, regs B): issue tile kt+2 (if any), then compute
    if (kt < 30) {
      STAGE(0);
      LOADB(bcA, mcA);
    }
    COMPUTE(1, bcB, mcB);
    __syncthreads();
  }
#undef COMPUTE
#undef LOADB
#undef STAGE

  // ---- normalize and store X[b,s,h*64+d] (f16) ----
#pragma unroll
  for (int bb = 0; bb < 2; ++bb) {
    const float inv = 1.0f / lrow[bb];
    float invq[4];
#pragma unroll
    for (int j = 0; j < 4; ++j) invq[j] = __shfl(inv, l4 * 4 + j);
#pragma unroll
    for (int j = 0; j < 4; ++j) {
      const int qrow = q0 + l4 * 4 + j;
#pragma unroll
      for (int n = 0; n < 4; ++n)
        X[((size_t)bb * 2048 + qrow) * 1024 + h * 64 + n * 16 + l15] =
            (f16)(oacc[bb][n][j] * invq[j]);
    }
  }
}

// ---------------- host ------------------------------------------------------
extern "C" void kernel_launch(void* const* d_in, const int* in_sizes, int n_in,
                              void* d_out, int out_size, void* d_ws, size_t ws_size,
                              hipStream_t stream) {
  const float* query = (const float*)d_in[0];
  const float* key_ = (const float*)d_in[1];
  const float* value = (const float*)d_in[2];
  const uint8_t* mask = (const uint8_t*)d_in[3];
  const float* bias = (const float*)d_in[4];
  const float* Wq = (const float*)d_in[5];
  const float* bq = (const float*)d_in[6];
  const float* Wk = (const float*)d_in[7];
  const float* bk = (const float*)d_in[8];
  const float* Wv = (const float*)d_in[9];
  const float* bv = (const float*)d_in[10];
  const float* Wo = (const float*)d_in[11];
  const float* bo = (const float*)d_in[12];

  char* p = (char*)d_ws;
  f16* qh = (f16*)p; p += (size_t)4194304 * 2;   // contiguous cvt dst region:
  f16* kh = (f16*)p; p += (size_t)4194304 * 2;   // qh,kh,vh,wqh,wkh,wvh,woh
  f16* vh = (f16*)p; p += (size_t)4194304 * 2;
  f16* wqh = (f16*)p; p += (size_t)1048576 * 2;
  f16* wkh = (f16*)p; p += (size_t)1048576 * 2;
  f16* wvh = (f16*)p; p += (size_t)1048576 * 2;
  f16* woh = (f16*)p; p += (size_t)1048576 * 2;
  f16* Qp = (f16*)p; p += (size_t)4194304 * 2;
  f16* Kp = (f16*)p; p += (size_t)4194304 * 2;
  f16* Vt = (f16*)p; p += (size_t)4194304 * 2;
  f16* Xh = (f16*)p; p += (size_t)4194304 * 2;
  uint8_t* m8 = (uint8_t*)p; p += (size_t)8388608;
  int* flag = (int*)p; p += 256;
  if (ws_size < (size_t)(p - (char*)d_ws)) return;

  mask_detect<<<1, 256, 0, stream>>>(mask, flag);
  mask_canon<<<8192, 256, 0, stream>>>(mask, m8, flag);

  CvtSrcs cs;
  cs.s[0] = query; cs.s[1] = key_; cs.s[2] = value;
  cs.s[3] = Wq; cs.s[4] = Wk; cs.s[5] = Wv; cs.s[6] = Wo;
  cvt_all<<<16384, 256, 0, stream>>>(cs, qh);

  gemm_qkv<<<1536, 256, 0, stream>>>(qh, kh, vh, wqh, wkh, wvh, bq, bk, bv,
                                     Qp, Kp, Vt);

  attn_fwd<<<512, 256, 0, stream>>>(Qp, Kp, Vt, bias, m8, Xh);

  gemm_out<<<512, 256, 0, stream>>>(Xh, woh, bo, (float*)d_out);
}